// Round 15
// baseline (808.912 us; speedup 1.0000x reference)
//
#include <hip/hip_runtime.h>
#include <hip/hip_bf16.h>

#define NTOK 49
#define DIM 384
#define HEADS 12
#define SCALE 0.17677669529663687f

typedef __attribute__((ext_vector_type(8))) short bf16x8;
typedef __attribute__((ext_vector_type(4))) float f32x4;

#define MFMA16(a, b, c) __builtin_amdgcn_mfma_f32_16x16x32_bf16((a), (b), (c), 0, 0, 0)
#define PRIO_HI() __builtin_amdgcn_s_setprio(1)
#define PRIO_LO() __builtin_amdgcn_s_setprio(0)

__device__ __forceinline__ short f2bf(float f) {
  __hip_bfloat16 h = __float2bfloat16(f);
  return __builtin_bit_cast(short, h);
}

// Full-K=32 fragment from two K=16 C-tile slices (same relabel on A and B -> exact).
__device__ __forceinline__ bf16x8 pack8(f32x4 a, f32x4 b) {
  bf16x8 r;
#pragma unroll
  for (int i = 0; i < 4; ++i) { r[i] = f2bf(a[i]); r[i + 4] = f2bf(b[i]); }
  return r;
}

// ws layout:
//   wqT  : short [384][384]   elem off 0        (Wq^T row-major [n][k])
//   wkvT : short [768][384]   elem off 147456   (rows 0-383 K, 384-767 V)
//   wpT  : short [384][384]   elem off 442368
//   biasf: float [12][4][4][64][4] byte off 1179648  (fragment-ordered, coalesced)
// NOTE: dead tail prefetches may read ~1KB past a weight row; they stay inside
// d_ws (biasf follows wpT) and are never consumed.
#define WQT_OFF   0
#define WKVT_OFF  147456
#define WPT_OFF   442368
#define BIAS_BYTE_OFF 1179648
#define BIAS_ITEMS (12 * 4 * 4 * 64 * 4)

__global__ void prep_kernel(const float* __restrict__ qw, const float* __restrict__ kvw,
                            const float* __restrict__ pw, const float* __restrict__ bt,
                            short* __restrict__ wsS, float* __restrict__ biasf) {
  int id = blockIdx.x * 256 + threadIdx.x;
  const int SZ1 = 384 * 384;
  const int SZ2 = 768 * 384;
  const int SZ3 = 384 * 384;
  if (id < SZ1) {
    int n = id / 384, k = id % 384;
    wsS[WQT_OFF + id] = f2bf(qw[k * 384 + n]);
  } else if (id < SZ1 + SZ2) {
    int t = id - SZ1; int n = t / 384, k = t % 384;
    wsS[WKVT_OFF + t] = f2bf(kvw[k * 768 + n]);
  } else if (id < SZ1 + SZ2 + SZ3) {
    int t = id - (SZ1 + SZ2); int n = t / 384, k = t % 384;
    wsS[WPT_OFF + t] = f2bf(pw[k * 384 + n]);
  } else if (id < SZ1 + SZ2 + SZ3 + BIAS_ITEMS) {
    int t = id - (SZ1 + SZ2 + SZ3);
    // [h][qt][tb][l][i]: lane l of fragment (qt,tb) element i
    int i  = t & 3;
    int lm = (t >> 2) & 63;
    int tb = (t >> 8) & 3;
    int qt = (t >> 10) & 3;
    int h  = t >> 12;
    int q = qt * 16 + (lm & 15);
    int k = tb * 16 + (lm >> 4) * 4 + i;
    float v = 0.0f;
    if (q < NTOK && k < NTOK) {
      int idx = ((q / 7 - k / 7) + 6) * 13 + ((q % 7 - k % 7) + 6);
      v = bt[idx * HEADS + h];
    }
    biasf[t] = v;
  }
}

// LDS (shorts). Row stride 392 shorts = 196 dw == 4 mod 32: 16-row b128 frag
// reads land 2 lanes/bank (free). +64 elem pad so dead tail prefetches
// (row 48 + ko up to 472) stay inside the allocation.
#define LDS_ELEMS 38416
#define LDS_ALLOC (LDS_ELEMS + 64)
#define LDS_BYTES (LDS_ALLOC * 2)   // 76960 B -> 2 blocks/CU (153920 <= 160K)

// (256,2): 2 blocks/CU, 2 waves/SIMD, 256 regs/wave (VGPR+AGPR unified).
__global__ __launch_bounds__(256, 2)
void fused_kernel(const float* __restrict__ xe, const float* __restrict__ xb,
                  const float* __restrict__ qb, const float* __restrict__ kvb,
                  const float* __restrict__ pb,
                  const short* __restrict__ wqT, const short* __restrict__ wkvT,
                  const short* __restrict__ wpT, const float* __restrict__ biasf,
                  float* __restrict__ out) {
  extern __shared__ short lds[];
  short* X    = lds;             // x_body
  short* XE   = lds + 19208;     // x_edge; becomes OALL after barrier #2
  short* OALL = XE;

  const int b   = blockIdx.x;
  const int tid = threadIdx.x;
  const int u   = tid >> 6;      // wave 0..3, owns heads 3u..3u+2
  const int l   = tid & 63;
  const int m16 = l & 15;
  const int g   = l >> 4;
  const int h0  = u * 3;

  const f32x4 zf = {0.f, 0.f, 0.f, 0.f};

  // ---- stage x_edge -> XE and x_body -> X ----
  const float* xew = xe + (size_t)b * (NTOK * DIM);
  const float* xbw = xb + (size_t)b * (NTOK * DIM);
#pragma unroll 4
  for (int i4 = tid; i4 < 2 * 4704; i4 += 256) {
    int eb = i4 < 4704;
    int e = (eb ? i4 : i4 - 4704) * 4;
    const float* src = eb ? xew : xbw;
    short* dst = eb ? XE : X;
    int r = e / DIM, c = e % DIM;
    float4 v = *(const float4*)(src + e);
    ushort4 s;
    s.x = (unsigned short)f2bf(v.x); s.y = (unsigned short)f2bf(v.y);
    s.z = (unsigned short)f2bf(v.z); s.w = (unsigned short)f2bf(v.w);
    *(ushort4*)&dst[r * 392 + c] = s;
  }
  __syncthreads();   // [#1]

  // ===== Q pass: merged 3 heads (6 weight streams + xv, 2-deep pipeline) ====
  bf16x8 qfr[3][4];
  {
    f32x4 qc[6][4];   // t = hh*2 + dt
#pragma unroll
    for (int t = 0; t < 6; ++t)
#pragma unroll
      for (int tb = 0; tb < 4; ++tb) qc[t][tb] = zf;

    const short* wq[6];
    bf16x8 w0[6], w1[6];
#pragma unroll
    for (int t = 0; t < 6; ++t) {
      wq[t] = wqT + (size_t)((h0 + (t >> 1)) * 32 + (t & 1) * 16 + m16) * 384;
      w0[t] = *(const bf16x8*)(wq[t] + g * 8);
      w1[t] = *(const bf16x8*)(wq[t] + 32 + g * 8);
    }
    bf16x8 xA[4];
#pragma unroll
    for (int tb = 0; tb < 4; ++tb) {
      int tr = tb * 16 + m16; tr = tr < 49 ? tr : 48;
      xA[tb] = *(const bf16x8*)(&XE[tr * 392 + g * 8]);
    }
#pragma unroll 1
    for (int kk = 0; kk < 12; kk += 2) {
      const int ko2 = (kk + 2) * 32 + g * 8;   // tail iters: dead loads (padded)
      const int ko3 = (kk + 3) * 32 + g * 8;
      bf16x8 n0[6], n1[6];
#pragma unroll
      for (int t = 0; t < 6; ++t) n0[t] = *(const bf16x8*)(wq[t] + ko2);
#pragma unroll
      for (int t = 0; t < 6; ++t) n1[t] = *(const bf16x8*)(wq[t] + ko3);
      const int koB = (kk + 1) * 32 + g * 8;
      bf16x8 xB[4];
#pragma unroll
      for (int tb = 0; tb < 4; ++tb) {
        int tr = tb * 16 + m16; tr = tr < 49 ? tr : 48;
        xB[tb] = *(const bf16x8*)(&XE[tr * 392 + koB]);
      }
      PRIO_HI();
#pragma unroll
      for (int tb = 0; tb < 4; ++tb)
#pragma unroll
        for (int t = 0; t < 6; ++t) qc[t][tb] = MFMA16(w0[t], xA[tb], qc[t][tb]);
      PRIO_LO();
      // prefetch next even xv (full-iter distance)
#pragma unroll
      for (int tb = 0; tb < 4; ++tb) {
        int tr = tb * 16 + m16; tr = tr < 49 ? tr : 48;
        xA[tb] = *(const bf16x8*)(&XE[tr * 392 + ko2]);
      }
      PRIO_HI();
#pragma unroll
      for (int tb = 0; tb < 4; ++tb)
#pragma unroll
        for (int t = 0; t < 6; ++t) qc[t][tb] = MFMA16(w1[t], xB[tb], qc[t][tb]);
      PRIO_LO();
#pragma unroll
      for (int t = 0; t < 6; ++t) { w0[t] = n0[t]; w1[t] = n1[t]; }
    }
#pragma unroll
    for (int hh = 0; hh < 3; ++hh) {
      const int h = h0 + hh;
      float4 t0 = *(const float4*)(qb + h * 32 + g * 4);
      float4 t1 = *(const float4*)(qb + h * 32 + 16 + g * 4);
      f32x4 b0 = {t0.x, t0.y, t0.z, t0.w};
      f32x4 b1 = {t1.x, t1.y, t1.z, t1.w};
#pragma unroll
      for (int qt = 0; qt < 4; ++qt)
        qfr[hh][qt] = pack8((qc[hh * 2][qt] + b0) * SCALE, (qc[hh * 2 + 1][qt] + b1) * SCALE);
    }
  }
  __syncthreads();   // [#2] all XE reads done -> XE becomes OALL

  // == per head: merged K+V GEMM (2-deep weight + full-iter xv pipeline) ======
#pragma unroll
  for (int hh = 0; hh < 3; ++hh) {
    const int h = h0 + hh;

    f32x4 kc0[4], kc1[4], vc0[4], vc1[4];
#pragma unroll
    for (int tb = 0; tb < 4; ++tb) { kc0[tb] = zf; kc1[tb] = zf; vc0[tb] = zf; vc1[tb] = zf; }
    const short* wk0 = wkvT + (size_t)(h * 32 + m16) * 384;
    const short* wk1 = wkvT + (size_t)(h * 32 + 16 + m16) * 384;
    const short* wv0 = wkvT + (size_t)(384 + h * 32 + m16) * 384;
    const short* wv1 = wkvT + (size_t)(384 + h * 32 + 16 + m16) * 384;
    // weight slots: [k0,k1,v0,v1] x {even,odd}
    bf16x8 a0 = *(const bf16x8*)(wk0 + g * 8), a1 = *(const bf16x8*)(wk1 + g * 8);
    bf16x8 a2 = *(const bf16x8*)(wv0 + g * 8), a3 = *(const bf16x8*)(wv1 + g * 8);
    bf16x8 b0 = *(const bf16x8*)(wk0 + 32 + g * 8), b1 = *(const bf16x8*)(wk1 + 32 + g * 8);
    bf16x8 b2 = *(const bf16x8*)(wv0 + 32 + g * 8), b3 = *(const bf16x8*)(wv1 + 32 + g * 8);
    bf16x8 xA[4];
#pragma unroll
    for (int tb = 0; tb < 4; ++tb) {
      int tr = tb * 16 + m16; tr = tr < 49 ? tr : 48;
      xA[tb] = *(const bf16x8*)(&X[tr * 392 + g * 8]);
    }
#pragma unroll 1
    for (int kk = 0; kk < 12; kk += 2) {
      const int ko2 = (kk + 2) * 32 + g * 8;   // tail iters: dead loads (padded)
      const int ko3 = (kk + 3) * 32 + g * 8;
      bf16x8 n0 = *(const bf16x8*)(wk0 + ko2), n1 = *(const bf16x8*)(wk1 + ko2);
      bf16x8 n2 = *(const bf16x8*)(wv0 + ko2), n3 = *(const bf16x8*)(wv1 + ko2);
      bf16x8 m0 = *(const bf16x8*)(wk0 + ko3), m1 = *(const bf16x8*)(wk1 + ko3);
      bf16x8 m2 = *(const bf16x8*)(wv0 + ko3), m3 = *(const bf16x8*)(wv1 + ko3);
      const int koB = (kk + 1) * 32 + g * 8;
      bf16x8 xB[4];
#pragma unroll
      for (int tb = 0; tb < 4; ++tb) {
        int tr = tb * 16 + m16; tr = tr < 49 ? tr : 48;
        xB[tb] = *(const bf16x8*)(&X[tr * 392 + koB]);
      }
      // compute half A (weights a*, frags xA)
      PRIO_HI();
#pragma unroll
      for (int tb = 0; tb < 4; ++tb) {
        kc0[tb] = MFMA16(a0, xA[tb], kc0[tb]);
        kc1[tb] = MFMA16(a1, xA[tb], kc1[tb]);
        vc0[tb] = MFMA16(xA[tb], a2, vc0[tb]);
        vc1[tb] = MFMA16(xA[tb], a3, vc1[tb]);
      }
      PRIO_LO();
      // prefetch next even xv (full-iter distance)
#pragma unroll
      for (int tb = 0; tb < 4; ++tb) {
        int tr = tb * 16 + m16; tr = tr < 49 ? tr : 48;
        xA[tb] = *(const bf16x8*)(&X[tr * 392 + ko2]);
      }
      // compute half B (weights b*, frags xB)
      PRIO_HI();
#pragma unroll
      for (int tb = 0; tb < 4; ++tb) {
        kc0[tb] = MFMA16(b0, xB[tb], kc0[tb]);
        kc1[tb] = MFMA16(b1, xB[tb], kc1[tb]);
        vc0[tb] = MFMA16(xB[tb], b2, vc0[tb]);
        vc1[tb] = MFMA16(xB[tb], b3, vc1[tb]);
      }
      PRIO_LO();
      a0 = n0; a1 = n1; a2 = n2; a3 = n3;
      b0 = m0; b1 = m1; b2 = m2; b3 = m3;
    }
    // ---- fold biases, pack fragments ----
    bf16x8 kfr[4], vfr[2][2];
    {
      float4 t0 = *(const float4*)(kvb + h * 32 + g * 4);
      float4 t1 = *(const float4*)(kvb + h * 32 + 16 + g * 4);
      f32x4 c0 = {t0.x, t0.y, t0.z, t0.w};
      f32x4 c1 = {t1.x, t1.y, t1.z, t1.w};
#pragma unroll
      for (int tb = 0; tb < 4; ++tb) kfr[tb] = pack8(kc0[tb] + c0, kc1[tb] + c1);
    }
    {
      float vb0 = kvb[384 + h * 32 + m16];
      float vb1 = kvb[384 + h * 32 + 16 + m16];
      f32x4 bv0 = {vb0, vb0, vb0, vb0};
      f32x4 bv1 = {vb1, vb1, vb1, vb1};
#pragma unroll
      for (int t = 0; t < 2; ++t) {
        vfr[t][0] = pack8(vc0[2 * t] + bv0, vc0[2 * t + 1] + bv0);
        vfr[t][1] = pack8(vc1[2 * t] + bv1, vc1[2 * t + 1] + bv1);
      }
    }

    // ============ attention per q-tile; O flushed immediately ============
    const float4* bfh = (const float4*)biasf + (size_t)h * 4 * 4 * 64;
#pragma unroll
    for (int qt = 0; qt < 4; ++qt) {
      const float4* bq = bfh + qt * 4 * 64;
      float4 c0 = bq[l], c1 = bq[64 + l], c2 = bq[128 + l], c3 = bq[192 + l];
      f32x4 B0 = {c0.x, c0.y, c0.z, c0.w};
      f32x4 B1 = {c1.x, c1.y, c1.z, c1.w};
      f32x4 B2 = {c2.x, c2.y, c2.z, c2.w};
      f32x4 B3 = {c3.x, c3.y, c3.z, c3.w};
      f32x4 s[4];
      PRIO_HI();
#pragma unroll
      for (int tb = 0; tb < 4; ++tb) s[tb] = MFMA16(kfr[tb], qfr[hh][qt], zf);
      PRIO_LO();

      float sv[4][4];
#pragma unroll
      for (int i = 0; i < 4; ++i) {
        sv[0][i] = s[0][i] + B0[i];
        sv[1][i] = s[1][i] + B1[i];
        sv[2][i] = s[2][i] + B2[i];
        // tb=3: k = 48 + g*4 + i -> only (g==0,i==0) is a real key
        sv[3][i] = (g == 0 && i == 0) ? s[3][0] + B3[0] : -3.0e38f;
      }
      float mx = -3.0e38f;
#pragma unroll
      for (int tb = 0; tb < 4; ++tb)
#pragma unroll
        for (int i = 0; i < 4; ++i) mx = fmaxf(mx, sv[tb][i]);
      mx = fmaxf(mx, __shfl_xor(mx, 16));
      mx = fmaxf(mx, __shfl_xor(mx, 32));
      float sum = 0.f;
#pragma unroll
      for (int tb = 0; tb < 4; ++tb)
#pragma unroll
        for (int i = 0; i < 4; ++i) {
          float e = __expf(sv[tb][i] - mx);
          sv[tb][i] = e;
          sum += e;
        }
      sum += __shfl_xor(sum, 16);
      sum += __shfl_xor(sum, 32);
      float inv = 1.0f / sum;

      bf16x8 pfr[2];
#pragma unroll
      for (int t = 0; t < 2; ++t) {
        f32x4 lo = {sv[2 * t][0] * inv, sv[2 * t][1] * inv, sv[2 * t][2] * inv, sv[2 * t][3] * inv};
        f32x4 hi = {sv[2 * t + 1][0] * inv, sv[2 * t + 1][1] * inv, sv[2 * t + 1][2] * inv, sv[2 * t + 1][3] * inv};
        pfr[t] = pack8(lo, hi);
      }
      f32x4 o0 = zf, o1 = zf;
      PRIO_HI();
      o0 = MFMA16(pfr[0], vfr[0][0], o0); o0 = MFMA16(pfr[1], vfr[1][0], o0);
      o1 = MFMA16(pfr[0], vfr[0][1], o1); o1 = MFMA16(pfr[1], vfr[1][1], o1);
      PRIO_LO();
#pragma unroll
      for (int i = 0; i < 4; ++i) {
        int r = qt * 16 + g * 4 + i;
        if (r < 49) {
          OALL[r * 392 + h * 32 + m16]      = f2bf(o0[i]);
          OALL[r * 392 + h * 32 + 16 + m16] = f2bf(o1[i]);
        }
      }
    }
  }
  __syncthreads();   // [#3] OALL complete

  // ====== out-projection: wave u owns col-tiles u*6..u*6+5 (2-deep bw, af pp)
  {
    f32x4 pacc[4][6];
#pragma unroll
    for (int qt = 0; qt < 4; ++qt)
#pragma unroll
      for (int c = 0; c < 6; ++c) pacc[qt][c] = zf;

    int rq[4];
#pragma unroll
    for (int qt = 0; qt < 4; ++qt) {
      int r = qt * 16 + m16; rq[qt] = r < 49 ? r : 48;
    }
    const short* wp[6];
    bf16x8 w0[6], w1[6];
#pragma unroll
    for (int c = 0; c < 6; ++c) {
      wp[c] = wpT + (size_t)((u * 6 + c) * 16 + m16) * 384;
      w0[c] = *(const bf16x8*)(wp[c] + g * 8);
      w1[c] = *(const bf16x8*)(wp[c] + 32 + g * 8);
    }
    bf16x8 afA[4];
#pragma unroll
    for (int qt = 0; qt < 4; ++qt) afA[qt] = *(const bf16x8*)(&OALL[rq[qt] * 392 + g * 8]);
#pragma unroll 1
    for (int kk = 0; kk < 12; kk += 2) {
      const int ko2 = (kk + 2) * 32 + g * 8;   // tail iters: dead loads (padded)
      const int ko3 = (kk + 3) * 32 + g * 8;
      bf16x8 n0[6], n1[6];
#pragma unroll
      for (int c = 0; c < 6; ++c) n0[c] = *(const bf16x8*)(wp[c] + ko2);
#pragma unroll
      for (int c = 0; c < 6; ++c) n1[c] = *(const bf16x8*)(wp[c] + ko3);
      const int koB = (kk + 1) * 32 + g * 8;
      bf16x8 afB[4];
#pragma unroll
      for (int qt = 0; qt < 4; ++qt) afB[qt] = *(const bf16x8*)(&OALL[rq[qt] * 392 + koB]);
      // half A
      PRIO_HI();
#pragma unroll
      for (int c = 0; c < 6; ++c)
#pragma unroll
        for (int qt = 0; qt < 4; ++qt) pacc[qt][c] = MFMA16(afA[qt], w0[c], pacc[qt][c]);
      PRIO_LO();
      // prefetch next even af (full-iter distance)
#pragma unroll
      for (int qt = 0; qt < 4; ++qt) afA[qt] = *(const bf16x8*)(&OALL[rq[qt] * 392 + ko2]);
      // half B
      PRIO_HI();
#pragma unroll
      for (int c = 0; c < 6; ++c)
#pragma unroll
        for (int qt = 0; qt < 4; ++qt) pacc[qt][c] = MFMA16(afB[qt], w1[c], pacc[qt][c]);
      PRIO_LO();
#pragma unroll
      for (int c = 0; c < 6; ++c) { w0[c] = n0[c]; w1[c] = n1[c]; }
    }
    float* outw = out + (size_t)b * (NTOK * DIM);
#pragma unroll
    for (int c = 0; c < 6; ++c) {
      int col = (u * 6 + c) * 16 + m16;
      float pbv = pb[col];
#pragma unroll
      for (int qt = 0; qt < 4; ++qt)
#pragma unroll
        for (int i = 0; i < 4; ++i) {
          int r = qt * 16 + g * 4 + i;
          if (r < 49) outw[r * DIM + col] = pacc[qt][c][i] + pbv;
        }
    }
  }
}

extern "C" void kernel_launch(void* const* d_in, const int* in_sizes, int n_in,
                              void* d_out, int out_size, void* d_ws, size_t ws_size,
                              hipStream_t stream) {
  const float* xe  = (const float*)d_in[0];
  const float* xb  = (const float*)d_in[1];
  const float* qw  = (const float*)d_in[2];
  const float* qb  = (const float*)d_in[3];
  const float* kvw = (const float*)d_in[4];
  const float* kvb = (const float*)d_in[5];
  const float* pw  = (const float*)d_in[6];
  const float* pb  = (const float*)d_in[7];
  const float* bt  = (const float*)d_in[8];
  float* out = (float*)d_out;
  short* wsS = (short*)d_ws;
  float* biasf = (float*)((char*)d_ws + BIAS_BYTE_OFF);

  const int nwin = in_sizes[0] / (NTOK * DIM);

  const int prep_items = 384 * 384 + 768 * 384 + 384 * 384 + BIAS_ITEMS;
  prep_kernel<<<(prep_items + 255) / 256, 256, 0, stream>>>(qw, kvw, pw, bt, wsS, biasf);

  hipFuncSetAttribute((const void*)fused_kernel,
                      hipFuncAttributeMaxDynamicSharedMemorySize, LDS_BYTES);
  fused_kernel<<<nwin, 256, LDS_BYTES, stream>>>(
      xe, xb, qb, kvb, pb,
      wsS + WQT_OFF, wsS + WKVT_OFF, wsS + WPT_OFF, biasf, out);
}

// Round 16
// 798.721 us; speedup vs baseline: 1.0128x; 1.0128x over previous
//
#include <hip/hip_runtime.h>
#include <hip/hip_bf16.h>

#define NTOK 49
#define DIM 384
#define HEADS 12
#define SCALE 0.17677669529663687f

typedef __attribute__((ext_vector_type(8))) short bf16x8;
typedef __attribute__((ext_vector_type(4))) float f32x4;

#define MFMA16(a, b, c) __builtin_amdgcn_mfma_f32_16x16x32_bf16((a), (b), (c), 0, 0, 0)
#define PRIO_HI() __builtin_amdgcn_s_setprio(1)
#define PRIO_LO() __builtin_amdgcn_s_setprio(0)

__device__ __forceinline__ short f2bf(float f) {
  __hip_bfloat16 h = __float2bfloat16(f);
  return __builtin_bit_cast(short, h);
}

// Full-K=32 fragment from two K=16 C-tile slices (same relabel on A and B -> exact).
__device__ __forceinline__ bf16x8 pack8(f32x4 a, f32x4 b) {
  bf16x8 r;
#pragma unroll
  for (int i = 0; i < 4; ++i) { r[i] = f2bf(a[i]); r[i + 4] = f2bf(b[i]); }
  return r;
}

// ws layout:
//   wqT  : short [384][384]   elem off 0        (Wq^T row-major [n][k])
//   wkvT : short [768][384]   elem off 147456   (rows 0-383 K, 384-767 V)
//   wpT  : short [384][384]   elem off 442368
//   biasf: float [12][4][4][64][4] byte off 1179648  (fragment-ordered, coalesced)
#define WQT_OFF   0
#define WKVT_OFF  147456
#define WPT_OFF   442368
#define BIAS_BYTE_OFF 1179648
#define BIAS_ITEMS (12 * 4 * 4 * 64 * 4)

__global__ void prep_kernel(const float* __restrict__ qw, const float* __restrict__ kvw,
                            const float* __restrict__ pw, const float* __restrict__ bt,
                            short* __restrict__ wsS, float* __restrict__ biasf) {
  int id = blockIdx.x * 256 + threadIdx.x;
  const int SZ1 = 384 * 384;
  const int SZ2 = 768 * 384;
  const int SZ3 = 384 * 384;
  if (id < SZ1) {
    int n = id / 384, k = id % 384;
    wsS[WQT_OFF + id] = f2bf(qw[k * 384 + n]);
  } else if (id < SZ1 + SZ2) {
    int t = id - SZ1; int n = t / 384, k = t % 384;
    wsS[WKVT_OFF + t] = f2bf(kvw[k * 768 + n]);
  } else if (id < SZ1 + SZ2 + SZ3) {
    int t = id - (SZ1 + SZ2); int n = t / 384, k = t % 384;
    wsS[WPT_OFF + t] = f2bf(pw[k * 384 + n]);
  } else if (id < SZ1 + SZ2 + SZ3 + BIAS_ITEMS) {
    int t = id - (SZ1 + SZ2 + SZ3);
    // [h][qt][tb][l][i]: lane l of fragment (qt,tb) element i
    int i  = t & 3;
    int lm = (t >> 2) & 63;
    int tb = (t >> 8) & 3;
    int qt = (t >> 10) & 3;
    int h  = t >> 12;
    int q = qt * 16 + (lm & 15);
    int k = tb * 16 + (lm >> 4) * 4 + i;
    float v = 0.0f;
    if (q < NTOK && k < NTOK) {
      int idx = ((q / 7 - k / 7) + 6) * 13 + ((q % 7 - k % 7) + 6);
      v = bt[idx * HEADS + h];
    }
    biasf[t] = v;
  }
}

// LDS (shorts). Row stride 392 shorts = 196 dw == 4 mod 32: 16-row b128 frag
// reads land 2 lanes/bank (free).
#define LDS_ELEMS 38416
#define LDS_BYTES (LDS_ELEMS * 2)   // 76832 B -> 2 blocks/CU (153664 <= 160K)

// (256,2): 2 blocks/CU, 2 waves/SIMD, 256 regs/wave (VGPR+AGPR unified).
__global__ __launch_bounds__(256, 2)
void fused_kernel(const float* __restrict__ xe, const float* __restrict__ xb,
                  const float* __restrict__ qb, const float* __restrict__ kvb,
                  const float* __restrict__ pb,
                  const short* __restrict__ wqT, const short* __restrict__ wkvT,
                  const short* __restrict__ wpT, const float* __restrict__ biasf,
                  float* __restrict__ out) {
  extern __shared__ short lds[];
  short* X    = lds;             // x_body
  short* XE   = lds + 19208;     // x_edge; becomes OALL after barrier #2
  short* OALL = XE;

  const int b   = blockIdx.x;
  const int tid = threadIdx.x;
  const int u   = tid >> 6;      // wave 0..3, owns heads 3u..3u+2
  const int l   = tid & 63;
  const int m16 = l & 15;
  const int g   = l >> 4;
  const int h0  = u * 3;

  const f32x4 zf = {0.f, 0.f, 0.f, 0.f};

  // ---- stage x_edge -> XE and x_body -> X ----
  const float* xew = xe + (size_t)b * (NTOK * DIM);
  const float* xbw = xb + (size_t)b * (NTOK * DIM);
#pragma unroll 4
  for (int i4 = tid; i4 < 2 * 4704; i4 += 256) {
    int eb = i4 < 4704;
    int e = (eb ? i4 : i4 - 4704) * 4;
    const float* src = eb ? xew : xbw;
    short* dst = eb ? XE : X;
    int r = e / DIM, c = e % DIM;
    float4 v = *(const float4*)(src + e);
    ushort4 s;
    s.x = (unsigned short)f2bf(v.x); s.y = (unsigned short)f2bf(v.y);
    s.z = (unsigned short)f2bf(v.z); s.w = (unsigned short)f2bf(v.w);
    *(ushort4*)&dst[r * 392 + c] = s;
  }
  __syncthreads();   // [#1]

  // ===== Q pass: merged 3 heads (6 weight streams, 2-deep pipeline) =========
  bf16x8 qfr[3][4];
  {
    f32x4 qc[6][4];   // t = hh*2 + dt
#pragma unroll
    for (int t = 0; t < 6; ++t)
#pragma unroll
      for (int tb = 0; tb < 4; ++tb) qc[t][tb] = zf;

    const short* wq[6];
    bf16x8 w0[6], w1[6];
#pragma unroll
    for (int t = 0; t < 6; ++t) {
      wq[t] = wqT + (size_t)((h0 + (t >> 1)) * 32 + (t & 1) * 16 + m16) * 384;
      w0[t] = *(const bf16x8*)(wq[t] + g * 8);
      w1[t] = *(const bf16x8*)(wq[t] + 32 + g * 8);
    }
#pragma unroll 1
    for (int kk = 0; kk < 12; kk += 2) {
      const int ko2 = ((kk + 2) % 12) * 32 + g * 8;   // wrap: harmless dead load
      const int ko3 = ((kk + 3) % 12) * 32 + g * 8;
      bf16x8 n0[6], n1[6];
#pragma unroll
      for (int t = 0; t < 6; ++t) n0[t] = *(const bf16x8*)(wq[t] + ko2);
#pragma unroll
      for (int t = 0; t < 6; ++t) n1[t] = *(const bf16x8*)(wq[t] + ko3);
      const int koA = kk * 32 + g * 8;
      const int koB = (kk + 1) * 32 + g * 8;
      PRIO_HI();
#pragma unroll
      for (int tb = 0; tb < 4; ++tb) {
        int tr = tb * 16 + m16; tr = tr < 49 ? tr : 48;
        bf16x8 xv = *(const bf16x8*)(&XE[tr * 392 + koA]);
#pragma unroll
        for (int t = 0; t < 6; ++t) qc[t][tb] = MFMA16(w0[t], xv, qc[t][tb]);
      }
#pragma unroll
      for (int tb = 0; tb < 4; ++tb) {
        int tr = tb * 16 + m16; tr = tr < 49 ? tr : 48;
        bf16x8 xv = *(const bf16x8*)(&XE[tr * 392 + koB]);
#pragma unroll
        for (int t = 0; t < 6; ++t) qc[t][tb] = MFMA16(w1[t], xv, qc[t][tb]);
      }
      PRIO_LO();
#pragma unroll
      for (int t = 0; t < 6; ++t) { w0[t] = n0[t]; w1[t] = n1[t]; }
    }
#pragma unroll
    for (int hh = 0; hh < 3; ++hh) {
      const int h = h0 + hh;
      float4 t0 = *(const float4*)(qb + h * 32 + g * 4);
      float4 t1 = *(const float4*)(qb + h * 32 + 16 + g * 4);
      f32x4 b0 = {t0.x, t0.y, t0.z, t0.w};
      f32x4 b1 = {t1.x, t1.y, t1.z, t1.w};
#pragma unroll
      for (int qt = 0; qt < 4; ++qt)
        qfr[hh][qt] = pack8((qc[hh * 2][qt] + b0) * SCALE, (qc[hh * 2 + 1][qt] + b1) * SCALE);
    }
  }
  __syncthreads();   // [#2] all XE reads done -> XE becomes OALL

  // == per head: merged K+V GEMM (2-deep weight + full-iter xv pipeline) ======
#pragma unroll
  for (int hh = 0; hh < 3; ++hh) {
    const int h = h0 + hh;

    f32x4 kc0[4], kc1[4], vc0[4], vc1[4];
#pragma unroll
    for (int tb = 0; tb < 4; ++tb) { kc0[tb] = zf; kc1[tb] = zf; vc0[tb] = zf; vc1[tb] = zf; }
    const short* wk0 = wkvT + (size_t)(h * 32 + m16) * 384;
    const short* wk1 = wkvT + (size_t)(h * 32 + 16 + m16) * 384;
    const short* wv0 = wkvT + (size_t)(384 + h * 32 + m16) * 384;
    const short* wv1 = wkvT + (size_t)(384 + h * 32 + 16 + m16) * 384;
    // weight slots: [k0,k1,v0,v1] x {even,odd}
    bf16x8 a0 = *(const bf16x8*)(wk0 + g * 8), a1 = *(const bf16x8*)(wk1 + g * 8);
    bf16x8 a2 = *(const bf16x8*)(wv0 + g * 8), a3 = *(const bf16x8*)(wv1 + g * 8);
    bf16x8 b0 = *(const bf16x8*)(wk0 + 32 + g * 8), b1 = *(const bf16x8*)(wk1 + 32 + g * 8);
    bf16x8 b2 = *(const bf16x8*)(wv0 + 32 + g * 8), b3 = *(const bf16x8*)(wv1 + 32 + g * 8);
    bf16x8 xA[4];
#pragma unroll
    for (int tb = 0; tb < 4; ++tb) {
      int tr = tb * 16 + m16; tr = tr < 49 ? tr : 48;
      xA[tb] = *(const bf16x8*)(&X[tr * 392 + g * 8]);
    }
#pragma unroll 1
    for (int kk = 0; kk < 12; kk += 2) {
      const int ko2 = ((kk + 2) % 12) * 32 + g * 8;   // wrap: harmless dead load
      const int ko3 = ((kk + 3) % 12) * 32 + g * 8;
      bf16x8 n0 = *(const bf16x8*)(wk0 + ko2), n1 = *(const bf16x8*)(wk1 + ko2);
      bf16x8 n2 = *(const bf16x8*)(wv0 + ko2), n3 = *(const bf16x8*)(wv1 + ko2);
      bf16x8 m0 = *(const bf16x8*)(wk0 + ko3), m1 = *(const bf16x8*)(wk1 + ko3);
      bf16x8 m2 = *(const bf16x8*)(wv0 + ko3), m3 = *(const bf16x8*)(wv1 + ko3);
      const int koB = (kk + 1) * 32 + g * 8;
      bf16x8 xB[4];
#pragma unroll
      for (int tb = 0; tb < 4; ++tb) {
        int tr = tb * 16 + m16; tr = tr < 49 ? tr : 48;
        xB[tb] = *(const bf16x8*)(&X[tr * 392 + koB]);
      }
      // compute half A (weights a*, frags xA)
      PRIO_HI();
#pragma unroll
      for (int tb = 0; tb < 4; ++tb) {
        kc0[tb] = MFMA16(a0, xA[tb], kc0[tb]);
        kc1[tb] = MFMA16(a1, xA[tb], kc1[tb]);
        vc0[tb] = MFMA16(xA[tb], a2, vc0[tb]);
        vc1[tb] = MFMA16(xA[tb], a3, vc1[tb]);
      }
      PRIO_LO();
      // prefetch next even xv (full-iter distance)
#pragma unroll
      for (int tb = 0; tb < 4; ++tb) {
        int tr = tb * 16 + m16; tr = tr < 49 ? tr : 48;
        xA[tb] = *(const bf16x8*)(&X[tr * 392 + ko2]);
      }
      // compute half B (weights b*, frags xB)
      PRIO_HI();
#pragma unroll
      for (int tb = 0; tb < 4; ++tb) {
        kc0[tb] = MFMA16(b0, xB[tb], kc0[tb]);
        kc1[tb] = MFMA16(b1, xB[tb], kc1[tb]);
        vc0[tb] = MFMA16(xB[tb], b2, vc0[tb]);
        vc1[tb] = MFMA16(xB[tb], b3, vc1[tb]);
      }
      PRIO_LO();
      a0 = n0; a1 = n1; a2 = n2; a3 = n3;
      b0 = m0; b1 = m1; b2 = m2; b3 = m3;
    }
    // ---- fold biases, pack fragments ----
    bf16x8 kfr[4], vfr[2][2];
    {
      float4 t0 = *(const float4*)(kvb + h * 32 + g * 4);
      float4 t1 = *(const float4*)(kvb + h * 32 + 16 + g * 4);
      f32x4 c0 = {t0.x, t0.y, t0.z, t0.w};
      f32x4 c1 = {t1.x, t1.y, t1.z, t1.w};
#pragma unroll
      for (int tb = 0; tb < 4; ++tb) kfr[tb] = pack8(kc0[tb] + c0, kc1[tb] + c1);
    }
    {
      float vb0 = kvb[384 + h * 32 + m16];
      float vb1 = kvb[384 + h * 32 + 16 + m16];
      f32x4 bv0 = {vb0, vb0, vb0, vb0};
      f32x4 bv1 = {vb1, vb1, vb1, vb1};
#pragma unroll
      for (int t = 0; t < 2; ++t) {
        vfr[t][0] = pack8(vc0[2 * t] + bv0, vc0[2 * t + 1] + bv0);
        vfr[t][1] = pack8(vc1[2 * t] + bv1, vc1[2 * t + 1] + bv1);
      }
    }

    // ============ attention per q-tile; O flushed immediately ============
    const float4* bfh = (const float4*)biasf + (size_t)h * 4 * 4 * 64;
#pragma unroll
    for (int qt = 0; qt < 4; ++qt) {
      const float4* bq = bfh + qt * 4 * 64;
      float4 c0 = bq[l], c1 = bq[64 + l], c2 = bq[128 + l], c3 = bq[192 + l];
      f32x4 B0 = {c0.x, c0.y, c0.z, c0.w};
      f32x4 B1 = {c1.x, c1.y, c1.z, c1.w};
      f32x4 B2 = {c2.x, c2.y, c2.z, c2.w};
      f32x4 B3 = {c3.x, c3.y, c3.z, c3.w};
      f32x4 s[4];
      PRIO_HI();
#pragma unroll
      for (int tb = 0; tb < 4; ++tb) s[tb] = MFMA16(kfr[tb], qfr[hh][qt], zf);
      PRIO_LO();

      float sv[4][4];
#pragma unroll
      for (int i = 0; i < 4; ++i) {
        sv[0][i] = s[0][i] + B0[i];
        sv[1][i] = s[1][i] + B1[i];
        sv[2][i] = s[2][i] + B2[i];
        // tb=3: k = 48 + g*4 + i -> only (g==0,i==0) is a real key
        sv[3][i] = (g == 0 && i == 0) ? s[3][0] + B3[0] : -3.0e38f;
      }
      float mx = -3.0e38f;
#pragma unroll
      for (int tb = 0; tb < 4; ++tb)
#pragma unroll
        for (int i = 0; i < 4; ++i) mx = fmaxf(mx, sv[tb][i]);
      mx = fmaxf(mx, __shfl_xor(mx, 16));
      mx = fmaxf(mx, __shfl_xor(mx, 32));
      float sum = 0.f;
#pragma unroll
      for (int tb = 0; tb < 4; ++tb)
#pragma unroll
        for (int i = 0; i < 4; ++i) {
          float e = __expf(sv[tb][i] - mx);
          sv[tb][i] = e;
          sum += e;
        }
      sum += __shfl_xor(sum, 16);
      sum += __shfl_xor(sum, 32);
      float inv = 1.0f / sum;

      bf16x8 pfr[2];
#pragma unroll
      for (int t = 0; t < 2; ++t) {
        f32x4 lo = {sv[2 * t][0] * inv, sv[2 * t][1] * inv, sv[2 * t][2] * inv, sv[2 * t][3] * inv};
        f32x4 hi = {sv[2 * t + 1][0] * inv, sv[2 * t + 1][1] * inv, sv[2 * t + 1][2] * inv, sv[2 * t + 1][3] * inv};
        pfr[t] = pack8(lo, hi);
      }
      f32x4 o0 = zf, o1 = zf;
      PRIO_HI();
      o0 = MFMA16(pfr[0], vfr[0][0], o0); o0 = MFMA16(pfr[1], vfr[1][0], o0);
      o1 = MFMA16(pfr[0], vfr[0][1], o1); o1 = MFMA16(pfr[1], vfr[1][1], o1);
      PRIO_LO();
#pragma unroll
      for (int i = 0; i < 4; ++i) {
        int r = qt * 16 + g * 4 + i;
        if (r < 49) {
          OALL[r * 392 + h * 32 + m16]      = f2bf(o0[i]);
          OALL[r * 392 + h * 32 + 16 + m16] = f2bf(o1[i]);
        }
      }
    }
  }
  __syncthreads();   // [#3] OALL complete

  // ====== out-projection: wave u owns col-tiles u*6..u*6+5 (2-deep bw, af pp)
  {
    f32x4 pacc[4][6];
#pragma unroll
    for (int qt = 0; qt < 4; ++qt)
#pragma unroll
      for (int c = 0; c < 6; ++c) pacc[qt][c] = zf;

    int rq[4];
#pragma unroll
    for (int qt = 0; qt < 4; ++qt) {
      int r = qt * 16 + m16; rq[qt] = r < 49 ? r : 48;
    }
    const short* wp[6];
    bf16x8 w0[6], w1[6];
#pragma unroll
    for (int c = 0; c < 6; ++c) {
      wp[c] = wpT + (size_t)((u * 6 + c) * 16 + m16) * 384;
      w0[c] = *(const bf16x8*)(wp[c] + g * 8);
      w1[c] = *(const bf16x8*)(wp[c] + 32 + g * 8);
    }
    bf16x8 afA[4];
#pragma unroll
    for (int qt = 0; qt < 4; ++qt) afA[qt] = *(const bf16x8*)(&OALL[rq[qt] * 392 + g * 8]);
#pragma unroll 1
    for (int kk = 0; kk < 12; kk += 2) {
      const int ko2 = ((kk + 2) % 12) * 32 + g * 8;   // wrap: harmless dead load
      const int ko3 = ((kk + 3) % 12) * 32 + g * 8;
      bf16x8 n0[6], n1[6];
#pragma unroll
      for (int c = 0; c < 6; ++c) n0[c] = *(const bf16x8*)(wp[c] + ko2);
#pragma unroll
      for (int c = 0; c < 6; ++c) n1[c] = *(const bf16x8*)(wp[c] + ko3);
      const int koB = (kk + 1) * 32 + g * 8;
      bf16x8 afB[4];
#pragma unroll
      for (int qt = 0; qt < 4; ++qt) afB[qt] = *(const bf16x8*)(&OALL[rq[qt] * 392 + koB]);
      // half A
      PRIO_HI();
#pragma unroll
      for (int c = 0; c < 6; ++c)
#pragma unroll
        for (int qt = 0; qt < 4; ++qt) pacc[qt][c] = MFMA16(afA[qt], w0[c], pacc[qt][c]);
      PRIO_LO();
      // prefetch next even af (full-iter distance)
#pragma unroll
      for (int qt = 0; qt < 4; ++qt) afA[qt] = *(const bf16x8*)(&OALL[rq[qt] * 392 + ko2]);
      // half B
      PRIO_HI();
#pragma unroll
      for (int c = 0; c < 6; ++c)
#pragma unroll
        for (int qt = 0; qt < 4; ++qt) pacc[qt][c] = MFMA16(afB[qt], w1[c], pacc[qt][c]);
      PRIO_LO();
#pragma unroll
      for (int c = 0; c < 6; ++c) { w0[c] = n0[c]; w1[c] = n1[c]; }
    }
    float* outw = out + (size_t)b * (NTOK * DIM);
#pragma unroll
    for (int c = 0; c < 6; ++c) {
      int col = (u * 6 + c) * 16 + m16;
      float pbv = pb[col];
#pragma unroll
      for (int qt = 0; qt < 4; ++qt)
#pragma unroll
        for (int i = 0; i < 4; ++i) {
          int r = qt * 16 + g * 4 + i;
          if (r < 49) outw[r * DIM + col] = pacc[qt][c][i] + pbv;
        }
    }
  }
}

extern "C" void kernel_launch(void* const* d_in, const int* in_sizes, int n_in,
                              void* d_out, int out_size, void* d_ws, size_t ws_size,
                              hipStream_t stream) {
  const float* xe  = (const float*)d_in[0];
  const float* xb  = (const float*)d_in[1];
  const float* qw  = (const float*)d_in[2];
  const float* qb  = (const float*)d_in[3];
  const float* kvw = (const float*)d_in[4];
  const float* kvb = (const float*)d_in[5];
  const float* pw  = (const float*)d_in[6];
  const float* pb  = (const float*)d_in[7];
  const float* bt  = (const float*)d_in[8];
  float* out = (float*)d_out;
  short* wsS = (short*)d_ws;
  float* biasf = (float*)((char*)d_ws + BIAS_BYTE_OFF);

  const int nwin = in_sizes[0] / (NTOK * DIM);

  const int prep_items = 384 * 384 + 768 * 384 + 384 * 384 + BIAS_ITEMS;
  prep_kernel<<<(prep_items + 255) / 256, 256, 0, stream>>>(qw, kvw, pw, bt, wsS, biasf);

  hipFuncSetAttribute((const void*)fused_kernel,
                      hipFuncAttributeMaxDynamicSharedMemorySize, LDS_BYTES);
  fused_kernel<<<nwin, 256, LDS_BYTES, stream>>>(
      xe, xb, qb, kvb, pb,
      wsS + WQT_OFF, wsS + WKVT_OFF, wsS + WPT_OFF, biasf, out);
}

// Round 17
// 692.342 us; speedup vs baseline: 1.1684x; 1.1537x over previous
//
#include <hip/hip_runtime.h>
#include <hip/hip_bf16.h>

#define NTOK 49
#define DIM 384
#define HEADS 12
#define SCALE 0.17677669529663687f

typedef __attribute__((ext_vector_type(8))) short bf16x8;
typedef __attribute__((ext_vector_type(4))) float f32x4;

#define MFMA16(a, b, c) __builtin_amdgcn_mfma_f32_16x16x32_bf16((a), (b), (c), 0, 0, 0)

__device__ __forceinline__ short f2bf(float f) {
  __hip_bfloat16 h = __float2bfloat16(f);
  return __builtin_bit_cast(short, h);
}

// Full-K=32 fragment from two K=16 C-tile slices (same relabel on A and B -> exact).
__device__ __forceinline__ bf16x8 pack8(f32x4 a, f32x4 b) {
  bf16x8 r;
#pragma unroll
  for (int i = 0; i < 4; ++i) { r[i] = f2bf(a[i]); r[i + 4] = f2bf(b[i]); }
  return r;
}

// ws layout:
//   wqT  : short [384][384]   elem off 0        (Wq^T row-major [n][k])
//   wkvT : short [768][384]   elem off 147456   (rows 0-383 K, 384-767 V)
//   wpT  : short [384][384]   elem off 442368
//   biasf: float [12][4][4][64][4] byte off 1179648  (fragment-ordered, coalesced)
#define WQT_OFF   0
#define WKVT_OFF  147456
#define WPT_OFF   442368
#define BIAS_BYTE_OFF 1179648
#define BIAS_ITEMS (12 * 4 * 4 * 64 * 4)

__global__ void prep_kernel(const float* __restrict__ qw, const float* __restrict__ kvw,
                            const float* __restrict__ pw, const float* __restrict__ bt,
                            short* __restrict__ wsS, float* __restrict__ biasf) {
  int id = blockIdx.x * 256 + threadIdx.x;
  const int SZ1 = 384 * 384;
  const int SZ2 = 768 * 384;
  const int SZ3 = 384 * 384;
  if (id < SZ1) {
    int n = id / 384, k = id % 384;
    wsS[WQT_OFF + id] = f2bf(qw[k * 384 + n]);
  } else if (id < SZ1 + SZ2) {
    int t = id - SZ1; int n = t / 384, k = t % 384;
    wsS[WKVT_OFF + t] = f2bf(kvw[k * 768 + n]);
  } else if (id < SZ1 + SZ2 + SZ3) {
    int t = id - (SZ1 + SZ2); int n = t / 384, k = t % 384;
    wsS[WPT_OFF + t] = f2bf(pw[k * 384 + n]);
  } else if (id < SZ1 + SZ2 + SZ3 + BIAS_ITEMS) {
    int t = id - (SZ1 + SZ2 + SZ3);
    // [h][qt][tb][l][i]: lane l of fragment (qt,tb) element i
    int i  = t & 3;
    int lm = (t >> 2) & 63;
    int tb = (t >> 8) & 3;
    int qt = (t >> 10) & 3;
    int h  = t >> 12;
    int q = qt * 16 + (lm & 15);
    int k = tb * 16 + (lm >> 4) * 4 + i;
    float v = 0.0f;
    if (q < NTOK && k < NTOK) {
      int idx = ((q / 7 - k / 7) + 6) * 13 + ((q % 7 - k % 7) + 6);
      v = bt[idx * HEADS + h];
    }
    biasf[t] = v;
  }
}

// LDS (shorts). Row stride 392 shorts = 196 dw == 4 mod 32: 16-row b128 frag
// reads land 2 lanes/bank (free).
#define LDS_ELEMS 38416
#define LDS_BYTES (LDS_ELEMS * 2)   // 76832 B -> 2 blocks/CU (153664 <= 160K)

// (256,2): 2 blocks/CU, 2 waves/SIMD, 256 regs/wave (VGPR+AGPR unified).
__global__ __launch_bounds__(256, 2)
void fused_kernel(const float* __restrict__ xe, const float* __restrict__ xb,
                  const float* __restrict__ qb, const float* __restrict__ kvb,
                  const float* __restrict__ pb,
                  const short* __restrict__ wqT, const short* __restrict__ wkvT,
                  const short* __restrict__ wpT, const float* __restrict__ biasf,
                  float* __restrict__ out) {
  extern __shared__ short lds[];
  short* X    = lds;             // x_body
  short* XE   = lds + 19208;     // x_edge; becomes OALL after barrier #2
  short* OALL = XE;

  const int b   = blockIdx.x;
  const int tid = threadIdx.x;
  const int u   = tid >> 6;      // wave 0..3, owns heads 3u..3u+2
  const int l   = tid & 63;
  const int m16 = l & 15;
  const int g   = l >> 4;
  const int h0  = u * 3;

  const f32x4 zf = {0.f, 0.f, 0.f, 0.f};

  // ---- stage x_edge -> XE and x_body -> X ----
  const float* xew = xe + (size_t)b * (NTOK * DIM);
  const float* xbw = xb + (size_t)b * (NTOK * DIM);
#pragma unroll 4
  for (int i4 = tid; i4 < 2 * 4704; i4 += 256) {
    int eb = i4 < 4704;
    int e = (eb ? i4 : i4 - 4704) * 4;
    const float* src = eb ? xew : xbw;
    short* dst = eb ? XE : X;
    int r = e / DIM, c = e % DIM;
    float4 v = *(const float4*)(src + e);
    ushort4 s;
    s.x = (unsigned short)f2bf(v.x); s.y = (unsigned short)f2bf(v.y);
    s.z = (unsigned short)f2bf(v.z); s.w = (unsigned short)f2bf(v.w);
    *(ushort4*)&dst[r * 392 + c] = s;
  }
  __syncthreads();   // [#1]

  // ===== Q pass: merged 3 heads (6 weight streams, 2-deep pipeline) =========
  bf16x8 qfr[3][4];
  {
    f32x4 qc[6][4];   // t = hh*2 + dt
#pragma unroll
    for (int t = 0; t < 6; ++t)
#pragma unroll
      for (int tb = 0; tb < 4; ++tb) qc[t][tb] = zf;

    const short* wq[6];
    bf16x8 w0[6], w1[6];
#pragma unroll
    for (int t = 0; t < 6; ++t) {
      wq[t] = wqT + (size_t)((h0 + (t >> 1)) * 32 + (t & 1) * 16 + m16) * 384;
      w0[t] = *(const bf16x8*)(wq[t] + g * 8);
      w1[t] = *(const bf16x8*)(wq[t] + 32 + g * 8);
    }
#pragma unroll 1
    for (int kk = 0; kk < 12; kk += 2) {
      const int ko2 = ((kk + 2) % 12) * 32 + g * 8;   // wrap: harmless dead load
      const int ko3 = ((kk + 3) % 12) * 32 + g * 8;
      bf16x8 n0[6], n1[6];
#pragma unroll
      for (int t = 0; t < 6; ++t) n0[t] = *(const bf16x8*)(wq[t] + ko2);
#pragma unroll
      for (int t = 0; t < 6; ++t) n1[t] = *(const bf16x8*)(wq[t] + ko3);
      const int koA = kk * 32 + g * 8;
      const int koB = (kk + 1) * 32 + g * 8;
#pragma unroll
      for (int tb = 0; tb < 4; ++tb) {
        int tr = tb * 16 + m16; tr = tr < 49 ? tr : 48;
        bf16x8 xv = *(const bf16x8*)(&XE[tr * 392 + koA]);
#pragma unroll
        for (int t = 0; t < 6; ++t) qc[t][tb] = MFMA16(w0[t], xv, qc[t][tb]);
      }
#pragma unroll
      for (int tb = 0; tb < 4; ++tb) {
        int tr = tb * 16 + m16; tr = tr < 49 ? tr : 48;
        bf16x8 xv = *(const bf16x8*)(&XE[tr * 392 + koB]);
#pragma unroll
        for (int t = 0; t < 6; ++t) qc[t][tb] = MFMA16(w1[t], xv, qc[t][tb]);
      }
#pragma unroll
      for (int t = 0; t < 6; ++t) { w0[t] = n0[t]; w1[t] = n1[t]; }
    }
#pragma unroll
    for (int hh = 0; hh < 3; ++hh) {
      const int h = h0 + hh;
      float4 t0 = *(const float4*)(qb + h * 32 + g * 4);
      float4 t1 = *(const float4*)(qb + h * 32 + 16 + g * 4);
      f32x4 b0 = {t0.x, t0.y, t0.z, t0.w};
      f32x4 b1 = {t1.x, t1.y, t1.z, t1.w};
#pragma unroll
      for (int qt = 0; qt < 4; ++qt)
        qfr[hh][qt] = pack8((qc[hh * 2][qt] + b0) * SCALE, (qc[hh * 2 + 1][qt] + b1) * SCALE);
    }
  }
  __syncthreads();   // [#2] all XE reads done -> XE becomes OALL

  // == per head: merged K+V GEMM (2-deep weight + full-iter xv pipeline) ======
#pragma unroll
  for (int hh = 0; hh < 3; ++hh) {
    const int h = h0 + hh;

    f32x4 kc0[4], kc1[4], vc0[4], vc1[4];
#pragma unroll
    for (int tb = 0; tb < 4; ++tb) { kc0[tb] = zf; kc1[tb] = zf; vc0[tb] = zf; vc1[tb] = zf; }
    const short* wk0 = wkvT + (size_t)(h * 32 + m16) * 384;
    const short* wk1 = wkvT + (size_t)(h * 32 + 16 + m16) * 384;
    const short* wv0 = wkvT + (size_t)(384 + h * 32 + m16) * 384;
    const short* wv1 = wkvT + (size_t)(384 + h * 32 + 16 + m16) * 384;
    // weight slots: [k0,k1,v0,v1] x {even,odd}
    bf16x8 a0 = *(const bf16x8*)(wk0 + g * 8), a1 = *(const bf16x8*)(wk1 + g * 8);
    bf16x8 a2 = *(const bf16x8*)(wv0 + g * 8), a3 = *(const bf16x8*)(wv1 + g * 8);
    bf16x8 b0 = *(const bf16x8*)(wk0 + 32 + g * 8), b1 = *(const bf16x8*)(wk1 + 32 + g * 8);
    bf16x8 b2 = *(const bf16x8*)(wv0 + 32 + g * 8), b3 = *(const bf16x8*)(wv1 + 32 + g * 8);
    bf16x8 xA[4];
#pragma unroll
    for (int tb = 0; tb < 4; ++tb) {
      int tr = tb * 16 + m16; tr = tr < 49 ? tr : 48;
      xA[tb] = *(const bf16x8*)(&X[tr * 392 + g * 8]);
    }
#pragma unroll 1
    for (int kk = 0; kk < 12; kk += 2) {
      const int ko2 = ((kk + 2) % 12) * 32 + g * 8;   // wrap: harmless dead load
      const int ko3 = ((kk + 3) % 12) * 32 + g * 8;
      bf16x8 n0 = *(const bf16x8*)(wk0 + ko2), n1 = *(const bf16x8*)(wk1 + ko2);
      bf16x8 n2 = *(const bf16x8*)(wv0 + ko2), n3 = *(const bf16x8*)(wv1 + ko2);
      bf16x8 m0 = *(const bf16x8*)(wk0 + ko3), m1 = *(const bf16x8*)(wk1 + ko3);
      bf16x8 m2 = *(const bf16x8*)(wv0 + ko3), m3 = *(const bf16x8*)(wv1 + ko3);
      const int koB = (kk + 1) * 32 + g * 8;
      bf16x8 xB[4];
#pragma unroll
      for (int tb = 0; tb < 4; ++tb) {
        int tr = tb * 16 + m16; tr = tr < 49 ? tr : 48;
        xB[tb] = *(const bf16x8*)(&X[tr * 392 + koB]);
      }
      // compute half A (weights a*, frags xA)
#pragma unroll
      for (int tb = 0; tb < 4; ++tb) {
        kc0[tb] = MFMA16(a0, xA[tb], kc0[tb]);
        kc1[tb] = MFMA16(a1, xA[tb], kc1[tb]);
        vc0[tb] = MFMA16(xA[tb], a2, vc0[tb]);
        vc1[tb] = MFMA16(xA[tb], a3, vc1[tb]);
      }
      // prefetch next even xv (full-iter distance)
#pragma unroll
      for (int tb = 0; tb < 4; ++tb) {
        int tr = tb * 16 + m16; tr = tr < 49 ? tr : 48;
        xA[tb] = *(const bf16x8*)(&X[tr * 392 + ko2]);
      }
      // compute half B (weights b*, frags xB)
#pragma unroll
      for (int tb = 0; tb < 4; ++tb) {
        kc0[tb] = MFMA16(b0, xB[tb], kc0[tb]);
        kc1[tb] = MFMA16(b1, xB[tb], kc1[tb]);
        vc0[tb] = MFMA16(xB[tb], b2, vc0[tb]);
        vc1[tb] = MFMA16(xB[tb], b3, vc1[tb]);
      }
      a0 = n0; a1 = n1; a2 = n2; a3 = n3;
      b0 = m0; b1 = m1; b2 = m2; b3 = m3;
    }
    // ---- fold biases, pack fragments ----
    bf16x8 kfr[4], vfr[2][2];
    {
      float4 t0 = *(const float4*)(kvb + h * 32 + g * 4);
      float4 t1 = *(const float4*)(kvb + h * 32 + 16 + g * 4);
      f32x4 c0 = {t0.x, t0.y, t0.z, t0.w};
      f32x4 c1 = {t1.x, t1.y, t1.z, t1.w};
#pragma unroll
      for (int tb = 0; tb < 4; ++tb) kfr[tb] = pack8(kc0[tb] + c0, kc1[tb] + c1);
    }
    {
      float vb0 = kvb[384 + h * 32 + m16];
      float vb1 = kvb[384 + h * 32 + 16 + m16];
      f32x4 bv0 = {vb0, vb0, vb0, vb0};
      f32x4 bv1 = {vb1, vb1, vb1, vb1};
#pragma unroll
      for (int t = 0; t < 2; ++t) {
        vfr[t][0] = pack8(vc0[2 * t] + bv0, vc0[2 * t + 1] + bv0);
        vfr[t][1] = pack8(vc1[2 * t] + bv1, vc1[2 * t + 1] + bv1);
      }
    }

    // ============ attention per q-tile; O flushed immediately ============
    const float4* bfh = (const float4*)biasf + (size_t)h * 4 * 4 * 64;
#pragma unroll
    for (int qt = 0; qt < 4; ++qt) {
      const float4* bq = bfh + qt * 4 * 64;
      float4 c0 = bq[l], c1 = bq[64 + l], c2 = bq[128 + l], c3 = bq[192 + l];
      f32x4 B0 = {c0.x, c0.y, c0.z, c0.w};
      f32x4 B1 = {c1.x, c1.y, c1.z, c1.w};
      f32x4 B2 = {c2.x, c2.y, c2.z, c2.w};
      f32x4 B3 = {c3.x, c3.y, c3.z, c3.w};
      f32x4 s[4];
#pragma unroll
      for (int tb = 0; tb < 4; ++tb) s[tb] = MFMA16(kfr[tb], qfr[hh][qt], zf);

      float sv[4][4];
#pragma unroll
      for (int i = 0; i < 4; ++i) {
        sv[0][i] = s[0][i] + B0[i];
        sv[1][i] = s[1][i] + B1[i];
        sv[2][i] = s[2][i] + B2[i];
        // tb=3: k = 48 + g*4 + i -> only (g==0,i==0) is a real key
        sv[3][i] = (g == 0 && i == 0) ? s[3][0] + B3[0] : -3.0e38f;
      }
      float mx = -3.0e38f;
#pragma unroll
      for (int tb = 0; tb < 4; ++tb)
#pragma unroll
        for (int i = 0; i < 4; ++i) mx = fmaxf(mx, sv[tb][i]);
      mx = fmaxf(mx, __shfl_xor(mx, 16));
      mx = fmaxf(mx, __shfl_xor(mx, 32));
      float sum = 0.f;
#pragma unroll
      for (int tb = 0; tb < 4; ++tb)
#pragma unroll
        for (int i = 0; i < 4; ++i) {
          float e = __expf(sv[tb][i] - mx);
          sv[tb][i] = e;
          sum += e;
        }
      sum += __shfl_xor(sum, 16);
      sum += __shfl_xor(sum, 32);
      float inv = 1.0f / sum;

      bf16x8 pfr[2];
#pragma unroll
      for (int t = 0; t < 2; ++t) {
        f32x4 lo = {sv[2 * t][0] * inv, sv[2 * t][1] * inv, sv[2 * t][2] * inv, sv[2 * t][3] * inv};
        f32x4 hi = {sv[2 * t + 1][0] * inv, sv[2 * t + 1][1] * inv, sv[2 * t + 1][2] * inv, sv[2 * t + 1][3] * inv};
        pfr[t] = pack8(lo, hi);
      }
      f32x4 o0 = zf, o1 = zf;
      o0 = MFMA16(pfr[0], vfr[0][0], o0); o0 = MFMA16(pfr[1], vfr[1][0], o0);
      o1 = MFMA16(pfr[0], vfr[0][1], o1); o1 = MFMA16(pfr[1], vfr[1][1], o1);
#pragma unroll
      for (int i = 0; i < 4; ++i) {
        int r = qt * 16 + g * 4 + i;
        if (r < 49) {
          OALL[r * 392 + h * 32 + m16]      = f2bf(o0[i]);
          OALL[r * 392 + h * 32 + 16 + m16] = f2bf(o1[i]);
        }
      }
    }
  }
  __syncthreads();   // [#3] OALL complete

  // ====== out-projection: wave u owns col-tiles u*6..u*6+5 (2-deep bw, af pp)
  {
    f32x4 pacc[4][6];
#pragma unroll
    for (int qt = 0; qt < 4; ++qt)
#pragma unroll
      for (int c = 0; c < 6; ++c) pacc[qt][c] = zf;

    int rq[4];
#pragma unroll
    for (int qt = 0; qt < 4; ++qt) {
      int r = qt * 16 + m16; rq[qt] = r < 49 ? r : 48;
    }
    const short* wp[6];
    bf16x8 w0[6], w1[6];
#pragma unroll
    for (int c = 0; c < 6; ++c) {
      wp[c] = wpT + (size_t)((u * 6 + c) * 16 + m16) * 384;
      w0[c] = *(const bf16x8*)(wp[c] + g * 8);
      w1[c] = *(const bf16x8*)(wp[c] + 32 + g * 8);
    }
    bf16x8 afA[4];
#pragma unroll
    for (int qt = 0; qt < 4; ++qt) afA[qt] = *(const bf16x8*)(&OALL[rq[qt] * 392 + g * 8]);
#pragma unroll 1
    for (int kk = 0; kk < 12; kk += 2) {
      const int ko2 = ((kk + 2) % 12) * 32 + g * 8;   // wrap: harmless dead load
      const int ko3 = ((kk + 3) % 12) * 32 + g * 8;
      bf16x8 n0[6], n1[6];
#pragma unroll
      for (int c = 0; c < 6; ++c) n0[c] = *(const bf16x8*)(wp[c] + ko2);
#pragma unroll
      for (int c = 0; c < 6; ++c) n1[c] = *(const bf16x8*)(wp[c] + ko3);
      const int koB = (kk + 1) * 32 + g * 8;
      bf16x8 afB[4];
#pragma unroll
      for (int qt = 0; qt < 4; ++qt) afB[qt] = *(const bf16x8*)(&OALL[rq[qt] * 392 + koB]);
      // half A
#pragma unroll
      for (int c = 0; c < 6; ++c)
#pragma unroll
        for (int qt = 0; qt < 4; ++qt) pacc[qt][c] = MFMA16(afA[qt], w0[c], pacc[qt][c]);
      // prefetch next even af (full-iter distance)
#pragma unroll
      for (int qt = 0; qt < 4; ++qt) afA[qt] = *(const bf16x8*)(&OALL[rq[qt] * 392 + ko2]);
      // half B
#pragma unroll
      for (int c = 0; c < 6; ++c)
#pragma unroll
        for (int qt = 0; qt < 4; ++qt) pacc[qt][c] = MFMA16(afB[qt], w1[c], pacc[qt][c]);
#pragma unroll
      for (int c = 0; c < 6; ++c) { w0[c] = n0[c]; w1[c] = n1[c]; }
    }
    float* outw = out + (size_t)b * (NTOK * DIM);
#pragma unroll
    for (int c = 0; c < 6; ++c) {
      int col = (u * 6 + c) * 16 + m16;
      float pbv = pb[col];
#pragma unroll
      for (int qt = 0; qt < 4; ++qt)
#pragma unroll
        for (int i = 0; i < 4; ++i) {
          int r = qt * 16 + g * 4 + i;
          if (r < 49) outw[r * DIM + col] = pacc[qt][c][i] + pbv;
        }
    }
  }
}

extern "C" void kernel_launch(void* const* d_in, const int* in_sizes, int n_in,
                              void* d_out, int out_size, void* d_ws, size_t ws_size,
                              hipStream_t stream) {
  const float* xe  = (const float*)d_in[0];
  const float* xb  = (const float*)d_in[1];
  const float* qw  = (const float*)d_in[2];
  const float* qb  = (const float*)d_in[3];
  const float* kvw = (const float*)d_in[4];
  const float* kvb = (const float*)d_in[5];
  const float* pw  = (const float*)d_in[6];
  const float* pb  = (const float*)d_in[7];
  const float* bt  = (const float*)d_in[8];
  float* out = (float*)d_out;
  short* wsS = (short*)d_ws;
  float* biasf = (float*)((char*)d_ws + BIAS_BYTE_OFF);

  const int nwin = in_sizes[0] / (NTOK * DIM);

  const int prep_items = 384 * 384 + 768 * 384 + 384 * 384 + BIAS_ITEMS;
  prep_kernel<<<(prep_items + 255) / 256, 256, 0, stream>>>(qw, kvw, pw, bt, wsS, biasf);

  hipFuncSetAttribute((const void*)fused_kernel,
                      hipFuncAttributeMaxDynamicSharedMemorySize, LDS_BYTES);
  fused_kernel<<<nwin, 256, LDS_BYTES, stream>>>(
      xe, xb, qb, kvb, pb,
      wsS + WQT_OFF, wsS + WKVT_OFF, wsS + WPT_OFF, biasf, out);
}